// Round 2
// baseline (417.409 us; speedup 1.0000x reference)
//
#include <hip/hip_runtime.h>
#include <cstdint>
#include <cstddef>

#define HIDDEN   2880
#define QKV_N    5120      // (64 + 2*8)*64
#define OPROJ_K  4096      // 64*64
#define NTOK     2048
#define WIN      128
#define SM_SCALE 0.125f

typedef _Float16 half8  __attribute__((ext_vector_type(8)));
typedef _Float16 half4v __attribute__((ext_vector_type(4)));
typedef float    f32x4  __attribute__((ext_vector_type(4)));

__device__ __forceinline__ void gload16(const void* g, void* l) {
  // async global->LDS, 16B per lane; LDS dest = wave-uniform base + lane*16
  __builtin_amdgcn_global_load_lds((__attribute__((address_space(1))) void*)g,
                                   (__attribute__((address_space(3))) void*)l,
                                   16, 0, 0);
}

__device__ __forceinline__ _Float16 f2h(float f) { return (_Float16)f; }

// ---------------- RMSNorm: x[2048][2880] fp32 -> f16 normalized*scale ----------------
__global__ __launch_bounds__(256) void rmsnorm_kernel(const float* __restrict__ x,
                                                      const float* __restrict__ scale,
                                                      _Float16* __restrict__ out) {
  int row = blockIdx.x, t = threadIdx.x;
  const float4* xr = (const float4*)(x + (size_t)row * HIDDEN);
  const float4* sc = (const float4*)scale;
  float4 v0 = xr[t];
  float4 v1 = xr[t + 256];
  float4 v2 = (t < 208) ? xr[t + 512] : make_float4(0.f, 0.f, 0.f, 0.f);
  float ss = v0.x*v0.x + v0.y*v0.y + v0.z*v0.z + v0.w*v0.w
           + v1.x*v1.x + v1.y*v1.y + v1.z*v1.z + v1.w*v1.w
           + v2.x*v2.x + v2.y*v2.y + v2.z*v2.z + v2.w*v2.w;
  #pragma unroll
  for (int m = 1; m < 64; m <<= 1) ss += __shfl_xor(ss, m, 64);
  __shared__ float red[4];
  if ((t & 63) == 0) red[t >> 6] = ss;
  __syncthreads();
  float inv = 1.0f / sqrtf((red[0] + red[1] + red[2] + red[3]) * (1.0f / HIDDEN) + 1e-5f);
  _Float16* orow = out + (size_t)row * HIDDEN;
  auto store4 = [&](int c4, const float4& v, const float4& s) {
    half4v h;
    h[0] = f2h(v.x * inv * s.x); h[1] = f2h(v.y * inv * s.y);
    h[2] = f2h(v.z * inv * s.z); h[3] = f2h(v.w * inv * s.w);
    *(half4v*)(orow + (size_t)c4 * 4) = h;
  };
  store4(t, v0, sc[t]);
  store4(t + 256, v1, sc[t + 256]);
  if (t < 208) store4(t + 512, v2, sc[t + 512]);
}

// ------------- cast+transpose: W[K][N] fp32 -> Wt[Npad][K] f16 (rows>=N zeroed) -------------
__global__ __launch_bounds__(256) void cast_transpose_kernel(const float* __restrict__ W,
                                                             _Float16* __restrict__ Wt,
                                                             int K, int N) {
  __shared__ float tile[32][33];
  int n0 = blockIdx.x * 32, k0 = blockIdx.y * 32;
  int t = threadIdx.x;
  #pragma unroll
  for (int p = 0; p < 4; ++p) {
    int e = t + p * 256; int r = e >> 5, cc = e & 31;
    float vv = 0.f;
    if (n0 + cc < N) vv = W[(size_t)(k0 + r) * N + n0 + cc];
    tile[r][cc] = vv;
  }
  __syncthreads();
  {
    int r = t >> 3, c4 = (t & 7) * 4;       // r = n-local, c4 = k-local
    half4v h;
    #pragma unroll
    for (int u = 0; u < 4; ++u) h[u] = (_Float16)tile[c4 + u][r];
    *(half4v*)&Wt[(size_t)(n0 + r) * K + k0 + c4] = h;
  }
}

// ---------------- f16 MFMA GEMM: C[M][N] = A[M][K] * Bt[N][K]^T + bias (+resid) ----------------
// BM x 128 tile, BK=32, 256 thr = 4 waves (2x2), wave tile (BM/2) x 64.
// LDS chunk swizzle: physical 16B chunk = logical_k ^ ((row>>1)&3)  -> conflict-free ds_read_b128.
template <int BM, bool HALF_OUT>
__global__ __launch_bounds__(256, 4) void gemm_kernel(const _Float16* __restrict__ A,
                                                      const _Float16* __restrict__ Bt,
                                                      const float* __restrict__ bias,
                                                      const float* __restrict__ resid,
                                                      void* __restrict__ Cout,
                                                      int M, int N, int K) {
  constexpr int MI = BM / 32;            // 16-row tiles per wave
  constexpr int NA = (BM * 4) / 256;     // A chunk groups per thread
  __shared__ _Float16 Alds[BM * 32];
  __shared__ _Float16 Blds[128 * 32];
  int tid = threadIdx.x;
  int wave = tid >> 6, lane = tid & 63;
  int wm = wave >> 1, wn = wave & 1;
  int c = lane & 15, quad = lane >> 4;
  int m0 = blockIdx.y * BM, n0 = blockIdx.x * 128;

  const _Float16* gAp[NA]; _Float16* lAp[NA];
  #pragma unroll
  for (int i = 0; i < NA; ++i) {
    int p = wave * 64 + i * 256 + lane;
    int r = p >> 2;
    int lk = (p & 3) ^ ((r >> 1) & 3);
    gAp[i] = A + (size_t)(m0 + r) * K + lk * 8;
    lAp[i] = Alds + (size_t)(wave * 64 + i * 256) * 8;
  }
  const _Float16* gBp[2]; _Float16* lBp[2];
  #pragma unroll
  for (int i = 0; i < 2; ++i) {
    int p = wave * 64 + i * 256 + lane;
    int r = p >> 2;
    int lk = (p & 3) ^ ((r >> 1) & 3);
    gBp[i] = Bt + (size_t)(n0 + r) * K + lk * 8;
    lBp[i] = Blds + (size_t)(wave * 64 + i * 256) * 8;
  }

  int phys8 = (quad ^ ((c >> 1) & 3)) * 8;   // swizzled k-chunk offset (halves)
  f32x4 acc[MI][4] = {};
  int nIter = K >> 5;
  for (int kt = 0; kt < nIter; ++kt) {
    __syncthreads();                 // previous iter's LDS reads done
    #pragma unroll
    for (int i = 0; i < NA; ++i) { gload16(gAp[i], lAp[i]); gAp[i] += 32; }
    #pragma unroll
    for (int i = 0; i < 2; ++i)  { gload16(gBp[i], lBp[i]); gBp[i] += 32; }
    __syncthreads();                 // vmcnt drained -> tiles visible
    half8 a[MI], b[4];
    #pragma unroll
    for (int i = 0; i < MI; ++i) {
      int row = wm * (BM / 2) + i * 16 + c;
      a[i] = *(const half8*)&Alds[row * 32 + phys8];
    }
    #pragma unroll
    for (int j = 0; j < 4; ++j) {
      int row = wn * 64 + j * 16 + c;
      b[j] = *(const half8*)&Blds[row * 32 + phys8];
    }
    #pragma unroll
    for (int i = 0; i < MI; ++i)
      #pragma unroll
      for (int j = 0; j < 4; ++j)
        acc[i][j] = __builtin_amdgcn_mfma_f32_16x16x32_f16(a[i], b[j], acc[i][j], 0, 0, 0);
  }

  // epilogue: C layout col=lane&15, row=quad*4+reg
  #pragma unroll
  for (int i = 0; i < MI; ++i) {
    int row = m0 + wm * (BM / 2) + i * 16 + quad * 4;
    #pragma unroll
    for (int j = 0; j < 4; ++j) {
      int col = n0 + wn * 64 + j * 16 + c;
      if (col < N) {
        float bv = bias[col];
        #pragma unroll
        for (int r = 0; r < 4; ++r) {
          float v = acc[i][j][r] + bv;
          if (resid) v += resid[(size_t)(row + r) * N + col];
          if (HALF_OUT) ((_Float16*)Cout)[(size_t)(row + r) * N + col] = f2h(v);
          else          ((float*)Cout)[(size_t)(row + r) * N + col] = v;
        }
      }
    }
  }
}

// ---------------- RoPE (YaRN) + split to q/k/v f16 ----------------
__global__ __launch_bounds__(256) void rope_kernel(const _Float16* __restrict__ qkv,
                                                   _Float16* __restrict__ qh,
                                                   _Float16* __restrict__ kh,
                                                   _Float16* __restrict__ vh) {
  int tok = blockIdx.x, t = threadIdx.x;
  __shared__ float cs[32], sn[32];
  if (t < 32) {
    const double PI = 3.14159265358979323846;
    double i = (double)t;
    double lf = log(150000.0);
    double freq = exp(lf * (i / 32.0));
    double interp = 1.0 / (32.0 * freq);
    double extrap = 1.0 / freq;
    double low  = 32.0 * log(4096.0 / (32.0 * 2.0 * PI)) / lf;
    double high = 32.0 * log(4096.0 / (2.0 * PI)) / lf;
    double ramp = (i - low) / (high - low);
    double mm = 1.0 - fmin(fmax(ramp, 0.0), 1.0);
    double invf = interp * (1.0 - mm) + extrap * mm;
    double ang = (double)tok * invf;
    double conc = 0.1 * log(32.0) + 1.0;
    cs[t] = (float)(cos(ang) * conc);
    sn[t] = (float)(sin(ang) * conc);
  }
  __syncthreads();
  const _Float16* row = qkv + (size_t)tok * QKV_N;
  #pragma unroll
  for (int p = 0; p < 8; ++p) {          // 64 q-heads x 32 pairs
    int pid = t + p * 256;
    int hh = pid >> 5, d = pid & 31;
    float x1 = (float)row[hh * 64 + d], x2 = (float)row[hh * 64 + d + 32];
    float cv = cs[d], sv = sn[d];
    _Float16* dst = qh + ((size_t)tok * 64 + hh) * 64 + d;
    dst[0]  = f2h(x1 * cv - x2 * sv);
    dst[32] = f2h(x2 * cv + x1 * sv);
  }
  {                                      // 8 kv-heads x 32 pairs
    int hh = t >> 5, d = t & 31;
    float x1 = (float)row[4096 + hh * 64 + d], x2 = (float)row[4096 + hh * 64 + d + 32];
    float cv = cs[d], sv = sn[d];
    _Float16* dst = kh + ((size_t)tok * 8 + hh) * 64 + d;
    dst[0]  = f2h(x1 * cv - x2 * sv);
    dst[32] = f2h(x2 * cv + x1 * sv);
  }
  #pragma unroll
  for (int p = 0; p < 2; ++p) {          // v passthrough
    int idx = t + p * 256;
    vh[(size_t)tok * 512 + idx] = row[4608 + idx];
  }
}

// ---------------- sliding-window GQA attention with sink ----------------
// block = (q-tile of 16 tokens) x (kv head). M = 8 qmult * 16 q = 128 rows, 144 keys = 9 n-tiles.
#define TQ 16
__global__ __launch_bounds__(256) void attn_kernel(const _Float16* __restrict__ qh,
                                                   const _Float16* __restrict__ kh,
                                                   const _Float16* __restrict__ vh,
                                                   const float* __restrict__ sink,
                                                   _Float16* __restrict__ attn_out) {
  __shared__ _Float16 Vt[64 * 160];    // [d][key], 20.0 KB, keys 144..159 zero
  __shared__ _Float16 Ps[128 * 160];   // [m][key] f16 probs, 40 KB, cols 144..159 zero
  int qt = blockIdx.x, kvh = blockIdx.y;
  int Q0 = qt * TQ;
  int kmin = (Q0 >= WIN) ? Q0 - WIN : 0;
  int nkv = Q0 + TQ - kmin;            // valid keys (<=144)
  int tid = threadIdx.x;
  int wave = tid >> 6, lane = tid & 63;
  int c = lane & 15, quad = lane >> 4;

  // ---- stage V^T into LDS (zero padding cols) ----
  #pragma unroll
  for (int p = 0; p < 5; ++p) {
    int cc = p * 256 + tid;            // 8 d-chunks x 160 cols = 1280
    int col = cc % 160;
    int d0 = (cc / 160) * 8;
    union { uint4 u4; _Float16 hv[8]; } buf;
    if (col < nkv) buf.u4 = *(const uint4*)(vh + ((size_t)(kmin + col) * 8 + kvh) * 64 + d0);
    else           buf.u4 = make_uint4(0, 0, 0, 0);
    #pragma unroll
    for (int uu = 0; uu < 8; ++uu) Vt[(d0 + uu) * 160 + col] = buf.hv[uu];
  }
  // ---- zero Ps pad columns 144..159 ----
  #pragma unroll
  for (int p = 0; p < 8; ++p) {
    int idx = p * 256 + tid;           // 128 rows x 16 cols
    Ps[(idx >> 4) * 160 + 144 + (idx & 15)] = (_Float16)0.f;
  }

  // ---- Q fragments from global (A-layout: m=lane&15, k=quad*8+j) ----
  half8 aq[2][2];
  #pragma unroll
  for (int i = 0; i < 2; ++i) {
    int qm = wave * 2 + i;
    #pragma unroll
    for (int ks = 0; ks < 2; ++ks)
      aq[i][ks] = *(const half8*)(qh + ((size_t)(Q0 + c) * 64 + kvh * 8 + qm) * 64 + ks * 32 + quad * 8);
  }

  // ---- S = Q K^T via MFMA, B-frags straight from global K ----
  f32x4 sacc[2][9] = {};
  #pragma unroll
  for (int j = 0; j < 9; ++j) {
    #pragma unroll
    for (int ks = 0; ks < 2; ++ks) {
      half8 bk = *(const half8*)(kh + ((size_t)(kmin + j * 16 + c) * 8 + kvh) * 64 + ks * 32 + quad * 8);
      #pragma unroll
      for (int i = 0; i < 2; ++i)
        sacc[i][j] = __builtin_amdgcn_mfma_f32_16x16x32_f16(aq[i][ks], bk, sacc[i][j], 0, 0, 0);
    }
  }

  // ---- in-register softmax (C layout: col=lane&15=key, row=quad*4+r=q) + sink ----
  #pragma unroll
  for (int i = 0; i < 2; ++i) {
    int qm = wave * 2 + i;
    float sk = sink[kvh * 8 + qm];
    #pragma unroll
    for (int r = 0; r < 4; ++r) {
      int qpos = Q0 + quad * 4 + r;
      float sv[9]; float mx = -3e38f;
      #pragma unroll
      for (int j = 0; j < 9; ++j) {
        int key = kmin + j * 16 + c;
        float s = sacc[i][j][r] * SM_SCALE;
        bool valid = (key <= qpos) && (qpos - key <= WIN);
        sv[j] = valid ? s : -3e38f;
        mx = fmaxf(mx, sv[j]);
      }
      #pragma unroll
      for (int msk = 1; msk < 16; msk <<= 1) mx = fmaxf(mx, __shfl_xor(mx, msk, 64));
      mx = fmaxf(mx, sk);
      float sum = 0.f; float pv[9];
      #pragma unroll
      for (int j = 0; j < 9; ++j) { float p = __expf(sv[j] - mx); pv[j] = p; sum += p; }
      #pragma unroll
      for (int msk = 1; msk < 16; msk <<= 1) sum += __shfl_xor(sum, msk, 64);
      sum += __expf(sk - mx);
      float inv = 1.0f / sum;
      int mrow = qm * 16 + quad * 4 + r;
      #pragma unroll
      for (int j = 0; j < 9; ++j)
        Ps[mrow * 160 + j * 16 + c] = f2h(pv[j] * inv);
    }
  }

  __syncthreads();   // Vt + Ps pads + P visible to all waves

  // ---- O = P V via MFMA (5 k-steps of 32 keys, tail zero-padded) ----
  f32x4 oacc[2][4] = {};
  #pragma unroll
  for (int ks = 0; ks < 5; ++ks) {
    half8 ap[2], bv[4];
    #pragma unroll
    for (int i = 0; i < 2; ++i)
      ap[i] = *(const half8*)&Ps[((wave * 2 + i) * 16 + c) * 160 + ks * 32 + quad * 8];
    #pragma unroll
    for (int j = 0; j < 4; ++j)
      bv[j] = *(const half8*)&Vt[(j * 16 + c) * 160 + ks * 32 + quad * 8];
    #pragma unroll
    for (int i = 0; i < 2; ++i)
      #pragma unroll
      for (int j = 0; j < 4; ++j)
        oacc[i][j] = __builtin_amdgcn_mfma_f32_16x16x32_f16(ap[i], bv[j], oacc[i][j], 0, 0, 0);
  }

  #pragma unroll
  for (int i = 0; i < 2; ++i) {
    int qm = wave * 2 + i;
    #pragma unroll
    for (int j = 0; j < 4; ++j)
      #pragma unroll
      for (int r = 0; r < 4; ++r) {
        int token = Q0 + quad * 4 + r;
        attn_out[(size_t)token * 4096 + (kvh * 8 + qm) * 64 + j * 16 + c] = f2h(oacc[i][j][r]);
      }
  }
}

// ---------------- launch ----------------
extern "C" void kernel_launch(void* const* d_in, const int* in_sizes, int n_in,
                              void* d_out, int out_size, void* d_ws, size_t ws_size,
                              hipStream_t stream) {
  (void)in_sizes; (void)n_in; (void)out_size; (void)ws_size;
  const float* x      = (const float*)d_in[0];
  const float* scale  = (const float*)d_in[1];
  const float* sink   = (const float*)d_in[2];
  const float* w_qkv  = (const float*)d_in[3];
  const float* b_qkv  = (const float*)d_in[4];
  const float* w_o    = (const float*)d_in[5];
  const float* b_o    = (const float*)d_in[6];
  float* out = (float*)d_out;

  char* ws = (char*)d_ws;
  size_t off = 0;
  auto alloc = [&](size_t bytes) { void* p = ws + off; off += (bytes + 255) & ~(size_t)255; return p; };
  _Float16* a_h   = (_Float16*)alloc((size_t)NTOK * HIDDEN * 2);   // 11.8 MB
  _Float16* wtq   = (_Float16*)alloc((size_t)QKV_N * HIDDEN * 2);  // 29.5 MB  [N][K]
  _Float16* wto   = (_Float16*)alloc((size_t)2944 * OPROJ_K * 2);  // 24.1 MB  [Npad][K]
  _Float16* qkv_h = (_Float16*)alloc((size_t)NTOK * QKV_N * 2);    // 21.0 MB
  _Float16* q_h   = (_Float16*)alloc((size_t)NTOK * 4096 * 2);     // 16.8 MB
  _Float16* k_h   = (_Float16*)alloc((size_t)NTOK * 512 * 2);      //  2.1 MB
  _Float16* v_h   = (_Float16*)alloc((size_t)NTOK * 512 * 2);      //  2.1 MB
  _Float16* at_h  = (_Float16*)alloc((size_t)NTOK * 4096 * 2);     // 16.8 MB  (~124 MB total)

  cast_transpose_kernel<<<dim3(QKV_N / 32, HIDDEN / 32), 256, 0, stream>>>(w_qkv, wtq, HIDDEN, QKV_N);
  cast_transpose_kernel<<<dim3(2944 / 32, OPROJ_K / 32), 256, 0, stream>>>(w_o, wto, OPROJ_K, HIDDEN);
  rmsnorm_kernel<<<NTOK, 256, 0, stream>>>(x, scale, a_h);
  gemm_kernel<64, true><<<dim3(QKV_N / 128, NTOK / 64), 256, 0, stream>>>(
      a_h, wtq, b_qkv, nullptr, qkv_h, NTOK, QKV_N, HIDDEN);
  rope_kernel<<<NTOK, 256, 0, stream>>>(qkv_h, q_h, k_h, v_h);
  attn_kernel<<<dim3(NTOK / TQ, 8), 256, 0, stream>>>(q_h, k_h, v_h, sink, at_h);
  gemm_kernel<64, false><<<dim3(23, NTOK / 64), 256, 0, stream>>>(
      at_h, wto, b_o, x, out, NTOK, HIDDEN, OPROJ_K);
}

// Round 3
// 353.843 us; speedup vs baseline: 1.1796x; 1.1796x over previous
//
#include <hip/hip_runtime.h>
#include <cstdint>
#include <cstddef>

#define HIDDEN   2880
#define QKV_N    5120      // (64 + 2*8)*64
#define OPROJ_K  4096      // 64*64
#define NTOK     2048
#define WIN      128
#define SM_SCALE 0.125f

typedef _Float16 half8  __attribute__((ext_vector_type(8)));
typedef _Float16 half4v __attribute__((ext_vector_type(4)));
typedef float    f32x4  __attribute__((ext_vector_type(4)));

__device__ __forceinline__ void gload16(const void* g, void* l) {
  // async global->LDS, 16B per lane; LDS dest = wave-uniform base + lane*16
  __builtin_amdgcn_global_load_lds((__attribute__((address_space(1))) void*)g,
                                   (__attribute__((address_space(3))) void*)l,
                                   16, 0, 0);
}

__device__ __forceinline__ _Float16 f2h(float f) { return (_Float16)f; }

// ---------------- YaRN rope table: tab[tok][d] = (cos,sin)*conc, d<32 ----------------
__global__ __launch_bounds__(256) void rope_tab_kernel(float2* __restrict__ tab) {
  int idx = blockIdx.x * 256 + threadIdx.x;    // 2048*32
  int tok = idx >> 5, d = idx & 31;
  const double PI = 3.14159265358979323846;
  double i = (double)d;
  double lf = log(150000.0);
  double freq = exp(lf * (i / 32.0));
  double interp = 1.0 / (32.0 * freq);
  double extrap = 1.0 / freq;
  double low  = 32.0 * log(4096.0 / (32.0 * 2.0 * PI)) / lf;
  double high = 32.0 * log(4096.0 / (2.0 * PI)) / lf;
  double ramp = (i - low) / (high - low);
  double mm = 1.0 - fmin(fmax(ramp, 0.0), 1.0);
  double invf = interp * (1.0 - mm) + extrap * mm;
  double ang = (double)tok * invf;
  double conc = 0.1 * log(32.0) + 1.0;
  tab[idx] = make_float2((float)(cos(ang) * conc), (float)(sin(ang) * conc));
}

// ---------------- RMSNorm: x[2048][2880] fp32 -> f16 normalized*scale ----------------
__global__ __launch_bounds__(256) void rmsnorm_kernel(const float* __restrict__ x,
                                                      const float* __restrict__ scale,
                                                      _Float16* __restrict__ out) {
  int row = blockIdx.x, t = threadIdx.x;
  const float4* xr = (const float4*)(x + (size_t)row * HIDDEN);
  const float4* sc = (const float4*)scale;
  float4 v0 = xr[t];
  float4 v1 = xr[t + 256];
  float4 v2 = (t < 208) ? xr[t + 512] : make_float4(0.f, 0.f, 0.f, 0.f);
  float ss = v0.x*v0.x + v0.y*v0.y + v0.z*v0.z + v0.w*v0.w
           + v1.x*v1.x + v1.y*v1.y + v1.z*v1.z + v1.w*v1.w
           + v2.x*v2.x + v2.y*v2.y + v2.z*v2.z + v2.w*v2.w;
  #pragma unroll
  for (int m = 1; m < 64; m <<= 1) ss += __shfl_xor(ss, m, 64);
  __shared__ float red[4];
  if ((t & 63) == 0) red[t >> 6] = ss;
  __syncthreads();
  float inv = 1.0f / sqrtf((red[0] + red[1] + red[2] + red[3]) * (1.0f / HIDDEN) + 1e-5f);
  _Float16* orow = out + (size_t)row * HIDDEN;
  auto store4 = [&](int c4, const float4& v, const float4& s) {
    half4v h;
    h[0] = f2h(v.x * inv * s.x); h[1] = f2h(v.y * inv * s.y);
    h[2] = f2h(v.z * inv * s.z); h[3] = f2h(v.w * inv * s.w);
    *(half4v*)(orow + (size_t)c4 * 4) = h;
  };
  store4(t, v0, sc[t]);
  store4(t + 256, v1, sc[t + 256]);
  if (t < 208) store4(t + 512, v2, sc[t + 512]);
}

// ------------- cast+transpose: W[K][N] fp32 -> Wt[Npad][K] f16 (rows>=N zeroed) -------------
__global__ __launch_bounds__(256) void cast_transpose_kernel(const float* __restrict__ W,
                                                             _Float16* __restrict__ Wt,
                                                             int K, int N) {
  __shared__ float tile[32][33];
  int n0 = blockIdx.x * 32, k0 = blockIdx.y * 32;
  int t = threadIdx.x;
  #pragma unroll
  for (int p = 0; p < 4; ++p) {
    int e = t + p * 256; int r = e >> 5, cc = e & 31;
    float vv = 0.f;
    if (n0 + cc < N) vv = W[(size_t)(k0 + r) * N + n0 + cc];
    tile[r][cc] = vv;
  }
  __syncthreads();
  {
    int r = t >> 3, c4 = (t & 7) * 4;       // r = n-local, c4 = k-local
    half4v h;
    #pragma unroll
    for (int u = 0; u < 4; ++u) h[u] = (_Float16)tile[c4 + u][r];
    *(half4v*)&Wt[(size_t)(n0 + r) * K + k0 + c4] = h;
  }
}

// ---------------- f16 MFMA GEMM: C[M][N] = A[M][K] * Bt[N][K]^T + bias ----------------
// BM x 128 tile, BK=64, 256 thr = 4 waves (2x2), wave tile (BM/2) x 64.
// LDS chunk swizzle: physical 16B chunk = logical ^ (row&7)  -> conflict-free ds_read_b128.
// QKV_MODE: f16 out with fused YaRN RoPE on cols < 4608 (q,k heads); else fp32 out + resid.
template <int BM, bool QKV_MODE>
__global__ __launch_bounds__(256, 2) void gemm_kernel(const _Float16* __restrict__ A,
                                                      const _Float16* __restrict__ Bt,
                                                      const float* __restrict__ bias,
                                                      const float* __restrict__ resid,
                                                      const float2* __restrict__ tab,
                                                      void* __restrict__ Cout,
                                                      int M, int N, int K) {
  constexpr int MI = BM / 32;            // 16-row tiles per wave
  constexpr int NA = BM / 32;            // A gload16 per thread (BM*8/256)
  __shared__ _Float16 Alds[BM * 64];
  __shared__ _Float16 Blds[128 * 64];
  int tid = threadIdx.x;
  int wave = tid >> 6, lane = tid & 63;
  int wm = wave >> 1, wn = wave & 1;
  int c = lane & 15, quad = lane >> 4;
  int m0 = blockIdx.y * BM, n0 = blockIdx.x * 128;

  const _Float16* gAp[NA]; _Float16* lAp[NA];
  #pragma unroll
  for (int i = 0; i < NA; ++i) {
    int p = wave * 64 + i * 256 + lane;
    int r = p >> 3;
    int kl = (p & 7) ^ (r & 7);
    gAp[i] = A + (size_t)(m0 + r) * K + kl * 8;
    lAp[i] = Alds + (size_t)(wave * 64 + i * 256) * 8;
  }
  const _Float16* gBp[4]; _Float16* lBp[4];
  #pragma unroll
  for (int i = 0; i < 4; ++i) {
    int p = wave * 64 + i * 256 + lane;
    int r = p >> 3;
    int kl = (p & 7) ^ (r & 7);
    gBp[i] = Bt + (size_t)(n0 + r) * K + kl * 8;
    lBp[i] = Blds + (size_t)(wave * 64 + i * 256) * 8;
  }

  int px[2];                             // swizzled chunk offsets (in halves)
  px[0] = ((0 * 4 + quad) ^ (c & 7)) * 8;
  px[1] = ((1 * 4 + quad) ^ (c & 7)) * 8;

  f32x4 acc[MI][4] = {};
  int nIter = K >> 6;
  for (int kt = 0; kt < nIter; ++kt) {
    __syncthreads();                 // previous iter's LDS reads done
    #pragma unroll
    for (int i = 0; i < NA; ++i) { gload16(gAp[i], lAp[i]); gAp[i] += 64; }
    #pragma unroll
    for (int i = 0; i < 4; ++i)  { gload16(gBp[i], lBp[i]); gBp[i] += 64; }
    __syncthreads();                 // vmcnt drained -> tiles visible
    half8 a[MI][2], b[4][2];
    #pragma unroll
    for (int i = 0; i < MI; ++i) {
      int row = wm * (BM / 2) + i * 16 + c;
      a[i][0] = *(const half8*)&Alds[row * 64 + px[0]];
      a[i][1] = *(const half8*)&Alds[row * 64 + px[1]];
    }
    #pragma unroll
    for (int j = 0; j < 4; ++j) {
      int row = wn * 64 + j * 16 + c;
      b[j][0] = *(const half8*)&Blds[row * 64 + px[0]];
      b[j][1] = *(const half8*)&Blds[row * 64 + px[1]];
    }
    #pragma unroll
    for (int i = 0; i < MI; ++i)
      #pragma unroll
      for (int j = 0; j < 4; ++j) {
        acc[i][j] = __builtin_amdgcn_mfma_f32_16x16x32_f16(a[i][0], b[j][0], acc[i][j], 0, 0, 0);
        acc[i][j] = __builtin_amdgcn_mfma_f32_16x16x32_f16(a[i][1], b[j][1], acc[i][j], 0, 0, 0);
      }
  }

  // epilogue: C layout col=lane&15, row=quad*4+reg
  if (QKV_MODE) {
    _Float16* outp = (_Float16*)Cout;
    bool ropeTile = (n0 < 4608);       // tiles 0..35 = q,k heads; 36..39 = v passthrough
    #pragma unroll
    for (int i = 0; i < MI; ++i) {
      int rowb = m0 + wm * (BM / 2) + i * 16 + quad * 4;
      if (ropeTile) {
        #pragma unroll
        for (int jp = 0; jp < 2; ++jp) {
          int col = n0 + wn * 64 + jp * 16 + c;   // d = jp*16+c (<32), partner at +32
          float b1 = bias[col], b2 = bias[col + 32];
          #pragma unroll
          for (int r = 0; r < 4; ++r) {
            float2 cs = tab[(size_t)(rowb + r) * 32 + jp * 16 + c];
            float x1 = acc[i][jp][r] + b1;
            float x2 = acc[i][jp + 2][r] + b2;
            outp[(size_t)(rowb + r) * QKV_N + col]      = f2h(x1 * cs.x - x2 * cs.y);
            outp[(size_t)(rowb + r) * QKV_N + col + 32] = f2h(x2 * cs.x + x1 * cs.y);
          }
        }
      } else {
        #pragma unroll
        for (int j = 0; j < 4; ++j) {
          int col = n0 + wn * 64 + j * 16 + c;
          float bv = bias[col];
          #pragma unroll
          for (int r = 0; r < 4; ++r)
            outp[(size_t)(rowb + r) * QKV_N + col] = f2h(acc[i][j][r] + bv);
        }
      }
    }
  } else {
    float* outp = (float*)Cout;
    #pragma unroll
    for (int i = 0; i < MI; ++i) {
      int rowb = m0 + wm * (BM / 2) + i * 16 + quad * 4;
      #pragma unroll
      for (int j = 0; j < 4; ++j) {
        int col = n0 + wn * 64 + j * 16 + c;
        if (col < N) {
          float bv = bias[col];
          #pragma unroll
          for (int r = 0; r < 4; ++r)
            outp[(size_t)(rowb + r) * N + col] =
                acc[i][j][r] + bv + resid[(size_t)(rowb + r) * N + col];
        }
      }
    }
  }
}

// ---------------- sliding-window GQA attention with sink ----------------
// block = (q-tile of 16 tokens) x (kv head). Reads q/k/v as strided views of qkv.
#define TQ 16
__global__ __launch_bounds__(256) void attn_kernel(const _Float16* __restrict__ qkv,
                                                   const float* __restrict__ sink,
                                                   _Float16* __restrict__ attn_out) {
  __shared__ _Float16 Vt[64 * 160];    // [d][key], 20.0 KB, keys 144..159 zero
  __shared__ _Float16 Ps[128 * 160];   // [m][key] f16 probs, 40 KB, cols 144..159 zero
  int qt = blockIdx.x, kvh = blockIdx.y;
  int Q0 = qt * TQ;
  int kmin = (Q0 >= WIN) ? Q0 - WIN : 0;
  int nkv = Q0 + TQ - kmin;            // valid keys (<=144)
  int tid = threadIdx.x;
  int wave = tid >> 6, lane = tid & 63;
  int c = lane & 15, quad = lane >> 4;

  // ---- stage V^T into LDS (zero padding cols); v at qkv col 4608 + kvh*64 ----
  #pragma unroll
  for (int p = 0; p < 5; ++p) {
    int cc = p * 256 + tid;            // 8 d-chunks x 160 cols = 1280
    int col = cc % 160;
    int d0 = (cc / 160) * 8;
    union { uint4 u4; _Float16 hv[8]; } buf;
    if (col < nkv) buf.u4 = *(const uint4*)(qkv + (size_t)(kmin + col) * QKV_N + 4608 + kvh * 64 + d0);
    else           buf.u4 = make_uint4(0, 0, 0, 0);
    #pragma unroll
    for (int uu = 0; uu < 8; ++uu) Vt[(d0 + uu) * 160 + col] = buf.hv[uu];
  }
  // ---- zero Ps pad columns 144..159 ----
  #pragma unroll
  for (int p = 0; p < 8; ++p) {
    int idx = p * 256 + tid;           // 128 rows x 16 cols
    Ps[(idx >> 4) * 160 + 144 + (idx & 15)] = (_Float16)0.f;
  }

  // ---- Q fragments from global (A-layout: m=lane&15, k=quad*8+j) ----
  half8 aq[2][2];
  #pragma unroll
  for (int i = 0; i < 2; ++i) {
    int qm = wave * 2 + i;
    #pragma unroll
    for (int ks = 0; ks < 2; ++ks)
      aq[i][ks] = *(const half8*)(qkv + (size_t)(Q0 + c) * QKV_N + (kvh * 8 + qm) * 64 + ks * 32 + quad * 8);
  }

  // ---- S = Q K^T via MFMA, B-frags straight from global K (qkv col 4096 + kvh*64) ----
  f32x4 sacc[2][9] = {};
  #pragma unroll
  for (int j = 0; j < 9; ++j) {
    #pragma unroll
    for (int ks = 0; ks < 2; ++ks) {
      half8 bk = *(const half8*)(qkv + (size_t)(kmin + j * 16 + c) * QKV_N + 4096 + kvh * 64 + ks * 32 + quad * 8);
      #pragma unroll
      for (int i = 0; i < 2; ++i)
        sacc[i][j] = __builtin_amdgcn_mfma_f32_16x16x32_f16(aq[i][ks], bk, sacc[i][j], 0, 0, 0);
    }
  }

  // ---- in-register softmax (C layout: col=lane&15=key, row=quad*4+r=q) + sink ----
  #pragma unroll
  for (int i = 0; i < 2; ++i) {
    int qm = wave * 2 + i;
    float sk = sink[kvh * 8 + qm];
    #pragma unroll
    for (int r = 0; r < 4; ++r) {
      int qpos = Q0 + quad * 4 + r;
      float sv[9]; float mx = -3e38f;
      #pragma unroll
      for (int j = 0; j < 9; ++j) {
        int key = kmin + j * 16 + c;
        float s = sacc[i][j][r] * SM_SCALE;
        bool valid = (key <= qpos) && (qpos - key <= WIN);
        sv[j] = valid ? s : -3e38f;
        mx = fmaxf(mx, sv[j]);
      }
      #pragma unroll
      for (int msk = 1; msk < 16; msk <<= 1) mx = fmaxf(mx, __shfl_xor(mx, msk, 64));
      mx = fmaxf(mx, sk);
      float sum = 0.f; float pv[9];
      #pragma unroll
      for (int j = 0; j < 9; ++j) { float p = __expf(sv[j] - mx); pv[j] = p; sum += p; }
      #pragma unroll
      for (int msk = 1; msk < 16; msk <<= 1) sum += __shfl_xor(sum, msk, 64);
      sum += __expf(sk - mx);
      float inv = 1.0f / sum;
      int mrow = qm * 16 + quad * 4 + r;
      #pragma unroll
      for (int j = 0; j < 9; ++j)
        Ps[mrow * 160 + j * 16 + c] = f2h(pv[j] * inv);
    }
  }

  __syncthreads();   // Vt + Ps pads + P visible to all waves

  // ---- O = P V via MFMA (5 k-steps of 32 keys, tail zero-padded) ----
  f32x4 oacc[2][4] = {};
  #pragma unroll
  for (int ks = 0; ks < 5; ++ks) {
    half8 ap[2], bv[4];
    #pragma unroll
    for (int i = 0; i < 2; ++i)
      ap[i] = *(const half8*)&Ps[((wave * 2 + i) * 16 + c) * 160 + ks * 32 + quad * 8];
    #pragma unroll
    for (int j = 0; j < 4; ++j)
      bv[j] = *(const half8*)&Vt[(j * 16 + c) * 160 + ks * 32 + quad * 8];
    #pragma unroll
    for (int i = 0; i < 2; ++i)
      #pragma unroll
      for (int j = 0; j < 4; ++j)
        oacc[i][j] = __builtin_amdgcn_mfma_f32_16x16x32_f16(ap[i], bv[j], oacc[i][j], 0, 0, 0);
  }

  #pragma unroll
  for (int i = 0; i < 2; ++i) {
    int qm = wave * 2 + i;
    #pragma unroll
    for (int j = 0; j < 4; ++j)
      #pragma unroll
      for (int r = 0; r < 4; ++r) {
        int token = Q0 + quad * 4 + r;
        attn_out[(size_t)token * 4096 + (kvh * 8 + qm) * 64 + j * 16 + c] = f2h(oacc[i][j][r]);
      }
  }
}

// ---------------- launch ----------------
extern "C" void kernel_launch(void* const* d_in, const int* in_sizes, int n_in,
                              void* d_out, int out_size, void* d_ws, size_t ws_size,
                              hipStream_t stream) {
  (void)in_sizes; (void)n_in; (void)out_size; (void)ws_size;
  const float* x      = (const float*)d_in[0];
  const float* scale  = (const float*)d_in[1];
  const float* sink   = (const float*)d_in[2];
  const float* w_qkv  = (const float*)d_in[3];
  const float* b_qkv  = (const float*)d_in[4];
  const float* w_o    = (const float*)d_in[5];
  const float* b_o    = (const float*)d_in[6];
  float* out = (float*)d_out;

  char* ws = (char*)d_ws;
  size_t off = 0;
  auto alloc = [&](size_t bytes) { void* p = ws + off; off += (bytes + 255) & ~(size_t)255; return p; };
  float2*   tab   = (float2*)alloc((size_t)NTOK * 32 * sizeof(float2));   // 0.5 MB
  _Float16* a_h   = (_Float16*)alloc((size_t)NTOK * HIDDEN * 2);   // 11.8 MB
  _Float16* wtq   = (_Float16*)alloc((size_t)QKV_N * HIDDEN * 2);  // 29.5 MB  [N][K]
  _Float16* wto   = (_Float16*)alloc((size_t)2944 * OPROJ_K * 2);  // 24.1 MB  [Npad][K]
  _Float16* qkv_h = (_Float16*)alloc((size_t)NTOK * QKV_N * 2);    // 21.0 MB (rope applied)
  _Float16* at_h  = (_Float16*)alloc((size_t)NTOK * 4096 * 2);     // 16.8 MB

  rope_tab_kernel<<<NTOK * 32 / 256, 256, 0, stream>>>(tab);
  cast_transpose_kernel<<<dim3(QKV_N / 32, HIDDEN / 32), 256, 0, stream>>>(w_qkv, wtq, HIDDEN, QKV_N);
  cast_transpose_kernel<<<dim3(2944 / 32, OPROJ_K / 32), 256, 0, stream>>>(w_o, wto, OPROJ_K, HIDDEN);
  rmsnorm_kernel<<<NTOK, 256, 0, stream>>>(x, scale, a_h);
  gemm_kernel<128, true><<<dim3(QKV_N / 128, NTOK / 128), 256, 0, stream>>>(
      a_h, wtq, b_qkv, nullptr, tab, qkv_h, NTOK, QKV_N, HIDDEN);
  attn_kernel<<<dim3(NTOK / TQ, 8), 256, 0, stream>>>(qkv_h, sink, at_h);
  gemm_kernel<64, false><<<dim3(23, NTOK / 64), 256, 0, stream>>>(
      at_h, wto, b_o, x, nullptr, out, NTOK, HIDDEN, OPROJ_K);
}

// Round 4
// 343.557 us; speedup vs baseline: 1.2150x; 1.0299x over previous
//
#include <hip/hip_runtime.h>
#include <cstdint>
#include <cstddef>

#define HIDDEN   2880
#define QKV_N    5120      // (64 + 2*8)*64
#define OPROJ_K  4096      // 64*64
#define NTOK     2048
#define WIN      128
#define SM_SCALE 0.125f

typedef _Float16 half8  __attribute__((ext_vector_type(8)));
typedef _Float16 half4v __attribute__((ext_vector_type(4)));
typedef float    f32x4  __attribute__((ext_vector_type(4)));

__device__ __forceinline__ void gload16(const void* g, void* l) {
  // async global->LDS, 16B per lane; LDS dest = wave-uniform base + lane*16
  __builtin_amdgcn_global_load_lds((__attribute__((address_space(1))) void*)g,
                                   (__attribute__((address_space(3))) void*)l,
                                   16, 0, 0);
}

__device__ __forceinline__ _Float16 f2h(float f) { return (_Float16)f; }

// ================= merged prep kernel =================
// blocks [0, NB_CQ)                : cast+transpose w_qkv -> wtq[N][K]
// blocks [NB_CQ, +NB_CO)           : cast+transpose w_o   -> wto[Npad][K]
// blocks [.., +NTOK)               : rmsnorm row
// blocks [.., +NB_ROPE)            : YaRN rope table
#define NB_CQ  (160 * 90)
#define NB_CO  (92 * 128)
#define NB_ROPE 256

__device__ __forceinline__ void cast_transpose_body(const float* __restrict__ W,
                                                    _Float16* __restrict__ Wt,
                                                    int K, int N, int n0, int k0,
                                                    float* tile /*32x33*/) {
  int t = threadIdx.x;
  #pragma unroll
  for (int p = 0; p < 4; ++p) {
    int e = t + p * 256; int r = e >> 5, cc = e & 31;
    float vv = 0.f;
    if (n0 + cc < N) vv = W[(size_t)(k0 + r) * N + n0 + cc];
    tile[r * 33 + cc] = vv;
  }
  __syncthreads();
  {
    int r = t >> 3, c4 = (t & 7) * 4;       // r = n-local, c4 = k-local
    half4v h;
    #pragma unroll
    for (int u = 0; u < 4; ++u) h[u] = (_Float16)tile[(c4 + u) * 33 + r];
    *(half4v*)&Wt[(size_t)(n0 + r) * K + k0 + c4] = h;
  }
}

__global__ __launch_bounds__(256) void prep_kernel(const float* __restrict__ x,
                                                   const float* __restrict__ scale,
                                                   const float* __restrict__ w_qkv,
                                                   const float* __restrict__ w_o,
                                                   _Float16* __restrict__ a_h,
                                                   _Float16* __restrict__ wtq,
                                                   _Float16* __restrict__ wto,
                                                   float2* __restrict__ tab) {
  __shared__ float smem[32 * 33];
  int b = blockIdx.x, t = threadIdx.x;
  if (b < NB_CQ) {
    cast_transpose_body(w_qkv, wtq, HIDDEN, QKV_N, (b % 160) * 32, (b / 160) * 32, smem);
    return;
  }
  b -= NB_CQ;
  if (b < NB_CO) {
    cast_transpose_body(w_o, wto, OPROJ_K, HIDDEN, (b % 92) * 32, (b / 92) * 32, smem);
    return;
  }
  b -= NB_CO;
  if (b < NTOK) {
    // ---- RMSNorm row b: fp32 -> f16 normalized*scale ----
    int row = b;
    const float4* xr = (const float4*)(x + (size_t)row * HIDDEN);
    const float4* sc = (const float4*)scale;
    float4 v0 = xr[t];
    float4 v1 = xr[t + 256];
    float4 v2 = (t < 208) ? xr[t + 512] : make_float4(0.f, 0.f, 0.f, 0.f);
    float ss = v0.x*v0.x + v0.y*v0.y + v0.z*v0.z + v0.w*v0.w
             + v1.x*v1.x + v1.y*v1.y + v1.z*v1.z + v1.w*v1.w
             + v2.x*v2.x + v2.y*v2.y + v2.z*v2.z + v2.w*v2.w;
    #pragma unroll
    for (int m = 1; m < 64; m <<= 1) ss += __shfl_xor(ss, m, 64);
    if ((t & 63) == 0) smem[t >> 6] = ss;
    __syncthreads();
    float inv = 1.0f / sqrtf((smem[0] + smem[1] + smem[2] + smem[3]) * (1.0f / HIDDEN) + 1e-5f);
    _Float16* orow = a_h + (size_t)row * HIDDEN;
    auto store4 = [&](int c4, const float4& v, const float4& s) {
      half4v h;
      h[0] = f2h(v.x * inv * s.x); h[1] = f2h(v.y * inv * s.y);
      h[2] = f2h(v.z * inv * s.z); h[3] = f2h(v.w * inv * s.w);
      *(half4v*)(orow + (size_t)c4 * 4) = h;
    };
    store4(t, v0, sc[t]);
    store4(t + 256, v1, sc[t + 256]);
    if (t < 208) store4(t + 512, v2, sc[t + 512]);
    return;
  }
  b -= NTOK;
  {
    // ---- YaRN rope table: tab[tok][d] = (cos,sin)*conc, d<32 ----
    int idx = b * 256 + t;               // 2048*32
    int tok = idx >> 5, d = idx & 31;
    const double PI = 3.14159265358979323846;
    double i = (double)d;
    double lf = log(150000.0);
    double freq = exp(lf * (i / 32.0));
    double interp = 1.0 / (32.0 * freq);
    double extrap = 1.0 / freq;
    double low  = 32.0 * log(4096.0 / (32.0 * 2.0 * PI)) / lf;
    double high = 32.0 * log(4096.0 / (2.0 * PI)) / lf;
    double ramp = (i - low) / (high - low);
    double mm = 1.0 - fmin(fmax(ramp, 0.0), 1.0);
    double invf = interp * (1.0 - mm) + extrap * mm;
    double ang = (double)tok * invf;
    double conc = 0.1 * log(32.0) + 1.0;
    tab[idx] = make_float2((float)(cos(ang) * conc), (float)(sin(ang) * conc));
  }
}

// ---------------- f16 MFMA GEMM: C[M][N] = A[M][K] * Bt[N][K]^T + bias ----------------
// BM x 128 tile, BK=64, 256 thr = 4 waves (2x2), wave tile (BM/2) x 64.
// LDS chunk swizzle: physical 16B chunk = logical ^ (row&7)  -> conflict-free ds_read_b128.
// QKV_MODE: f16 out with fused YaRN RoPE on cols < 4608 (q,k heads); else fp32 out + resid.
template <int BM, bool QKV_MODE>
__global__ __launch_bounds__(256, 2) void gemm_kernel(const _Float16* __restrict__ A,
                                                      const _Float16* __restrict__ Bt,
                                                      const float* __restrict__ bias,
                                                      const float* __restrict__ resid,
                                                      const float2* __restrict__ tab,
                                                      void* __restrict__ Cout,
                                                      int M, int N, int K) {
  constexpr int MI = BM / 32;            // 16-row tiles per wave
  constexpr int NA = BM / 32;            // A gload16 per thread (BM*8/256)
  __shared__ _Float16 Alds[BM * 64];
  __shared__ _Float16 Blds[128 * 64];
  int tid = threadIdx.x;
  int wave = tid >> 6, lane = tid & 63;
  int wm = wave >> 1, wn = wave & 1;
  int c = lane & 15, quad = lane >> 4;
  int m0 = blockIdx.y * BM, n0 = blockIdx.x * 128;

  const _Float16* gAp[NA]; _Float16* lAp[NA];
  #pragma unroll
  for (int i = 0; i < NA; ++i) {
    int p = wave * 64 + i * 256 + lane;
    int r = p >> 3;
    int kl = (p & 7) ^ (r & 7);
    gAp[i] = A + (size_t)(m0 + r) * K + kl * 8;
    lAp[i] = Alds + (size_t)(wave * 64 + i * 256) * 8;
  }
  const _Float16* gBp[4]; _Float16* lBp[4];
  #pragma unroll
  for (int i = 0; i < 4; ++i) {
    int p = wave * 64 + i * 256 + lane;
    int r = p >> 3;
    int kl = (p & 7) ^ (r & 7);
    gBp[i] = Bt + (size_t)(n0 + r) * K + kl * 8;
    lBp[i] = Blds + (size_t)(wave * 64 + i * 256) * 8;
  }

  int px[2];                             // swizzled chunk offsets (in halves)
  px[0] = ((0 * 4 + quad) ^ (c & 7)) * 8;
  px[1] = ((1 * 4 + quad) ^ (c & 7)) * 8;

  f32x4 acc[MI][4] = {};
  int nIter = K >> 6;
  for (int kt = 0; kt < nIter; ++kt) {
    __syncthreads();                 // previous iter's LDS reads done
    #pragma unroll
    for (int i = 0; i < NA; ++i) { gload16(gAp[i], lAp[i]); gAp[i] += 64; }
    #pragma unroll
    for (int i = 0; i < 4; ++i)  { gload16(gBp[i], lBp[i]); gBp[i] += 64; }
    __syncthreads();                 // vmcnt drained -> tiles visible
    half8 a[MI][2], b[4][2];
    #pragma unroll
    for (int i = 0; i < MI; ++i) {
      int row = wm * (BM / 2) + i * 16 + c;
      a[i][0] = *(const half8*)&Alds[row * 64 + px[0]];
      a[i][1] = *(const half8*)&Alds[row * 64 + px[1]];
    }
    #pragma unroll
    for (int j = 0; j < 4; ++j) {
      int row = wn * 64 + j * 16 + c;
      b[j][0] = *(const half8*)&Blds[row * 64 + px[0]];
      b[j][1] = *(const half8*)&Blds[row * 64 + px[1]];
    }
    #pragma unroll
    for (int i = 0; i < MI; ++i)
      #pragma unroll
      for (int j = 0; j < 4; ++j) {
        acc[i][j] = __builtin_amdgcn_mfma_f32_16x16x32_f16(a[i][0], b[j][0], acc[i][j], 0, 0, 0);
        acc[i][j] = __builtin_amdgcn_mfma_f32_16x16x32_f16(a[i][1], b[j][1], acc[i][j], 0, 0, 0);
      }
  }

  // epilogue: C layout col=lane&15, row=quad*4+reg
  if (QKV_MODE) {
    _Float16* outp = (_Float16*)Cout;
    bool ropeTile = (n0 < 4608);       // tiles 0..35 = q,k heads; 36..39 = v passthrough
    #pragma unroll
    for (int i = 0; i < MI; ++i) {
      int rowb = m0 + wm * (BM / 2) + i * 16 + quad * 4;
      if (ropeTile) {
        #pragma unroll
        for (int jp = 0; jp < 2; ++jp) {
          int col = n0 + wn * 64 + jp * 16 + c;   // d = jp*16+c (<32), partner at +32
          float b1 = bias[col], b2 = bias[col + 32];
          #pragma unroll
          for (int r = 0; r < 4; ++r) {
            float2 cs = tab[(size_t)(rowb + r) * 32 + jp * 16 + c];
            float x1 = acc[i][jp][r] + b1;
            float x2 = acc[i][jp + 2][r] + b2;
            outp[(size_t)(rowb + r) * QKV_N + col]      = f2h(x1 * cs.x - x2 * cs.y);
            outp[(size_t)(rowb + r) * QKV_N + col + 32] = f2h(x2 * cs.x + x1 * cs.y);
          }
        }
      } else {
        #pragma unroll
        for (int j = 0; j < 4; ++j) {
          int col = n0 + wn * 64 + j * 16 + c;
          float bv = bias[col];
          #pragma unroll
          for (int r = 0; r < 4; ++r)
            outp[(size_t)(rowb + r) * QKV_N + col] = f2h(acc[i][j][r] + bv);
        }
      }
    }
  } else {
    float* outp = (float*)Cout;
    #pragma unroll
    for (int i = 0; i < MI; ++i) {
      int rowb = m0 + wm * (BM / 2) + i * 16 + quad * 4;
      #pragma unroll
      for (int j = 0; j < 4; ++j) {
        int col = n0 + wn * 64 + j * 16 + c;
        if (col < N) {
          float bv = bias[col];
          #pragma unroll
          for (int r = 0; r < 4; ++r)
            outp[(size_t)(rowb + r) * N + col] =
                acc[i][j][r] + bv + resid[(size_t)(rowb + r) * N + col];
        }
      }
    }
  }
}

// ---------------- sliding-window GQA attention with sink ----------------
// block = (q-tile of 16 tokens) x (kv head). Reads q/k/v as strided views of qkv.
#define TQ 16
__global__ __launch_bounds__(256) void attn_kernel(const _Float16* __restrict__ qkv,
                                                   const float* __restrict__ sink,
                                                   _Float16* __restrict__ attn_out) {
  __shared__ _Float16 Vt[64 * 160];    // [d][key], 20.0 KB, keys 144..159 zero
  __shared__ _Float16 Ps[128 * 160];   // [m][key] f16 probs, 40 KB, cols 144..159 zero
  int qt = blockIdx.x, kvh = blockIdx.y;
  int Q0 = qt * TQ;
  int kmin = (Q0 >= WIN) ? Q0 - WIN : 0;
  int nkv = Q0 + TQ - kmin;            // valid keys (<=144)
  int tid = threadIdx.x;
  int wave = tid >> 6, lane = tid & 63;
  int c = lane & 15, quad = lane >> 4;

  // ---- stage V^T into LDS (zero padding cols); v at qkv col 4608 + kvh*64 ----
  #pragma unroll
  for (int p = 0; p < 5; ++p) {
    int cc = p * 256 + tid;            // 8 d-chunks x 160 cols = 1280
    int col = cc % 160;
    int d0 = (cc / 160) * 8;
    union { uint4 u4; _Float16 hv[8]; } buf;
    if (col < nkv) buf.u4 = *(const uint4*)(qkv + (size_t)(kmin + col) * QKV_N + 4608 + kvh * 64 + d0);
    else           buf.u4 = make_uint4(0, 0, 0, 0);
    #pragma unroll
    for (int uu = 0; uu < 8; ++uu) Vt[(d0 + uu) * 160 + col] = buf.hv[uu];
  }
  // ---- zero Ps pad columns 144..159 ----
  #pragma unroll
  for (int p = 0; p < 8; ++p) {
    int idx = p * 256 + tid;           // 128 rows x 16 cols
    Ps[(idx >> 4) * 160 + 144 + (idx & 15)] = (_Float16)0.f;
  }

  // ---- Q fragments from global (A-layout: m=lane&15, k=quad*8+j) ----
  half8 aq[2][2];
  #pragma unroll
  for (int i = 0; i < 2; ++i) {
    int qm = wave * 2 + i;
    #pragma unroll
    for (int ks = 0; ks < 2; ++ks)
      aq[i][ks] = *(const half8*)(qkv + (size_t)(Q0 + c) * QKV_N + (kvh * 8 + qm) * 64 + ks * 32 + quad * 8);
  }

  // ---- S = Q K^T via MFMA, B-frags straight from global K (qkv col 4096 + kvh*64) ----
  f32x4 sacc[2][9] = {};
  #pragma unroll
  for (int j = 0; j < 9; ++j) {
    #pragma unroll
    for (int ks = 0; ks < 2; ++ks) {
      half8 bk = *(const half8*)(qkv + (size_t)(kmin + j * 16 + c) * QKV_N + 4096 + kvh * 64 + ks * 32 + quad * 8);
      #pragma unroll
      for (int i = 0; i < 2; ++i)
        sacc[i][j] = __builtin_amdgcn_mfma_f32_16x16x32_f16(aq[i][ks], bk, sacc[i][j], 0, 0, 0);
    }
  }

  // ---- in-register softmax (C layout: col=lane&15=key, row=quad*4+r=q) + sink ----
  #pragma unroll
  for (int i = 0; i < 2; ++i) {
    int qm = wave * 2 + i;
    float sk = sink[kvh * 8 + qm];
    #pragma unroll
    for (int r = 0; r < 4; ++r) {
      int qpos = Q0 + quad * 4 + r;
      float sv[9]; float mx = -3e38f;
      #pragma unroll
      for (int j = 0; j < 9; ++j) {
        int key = kmin + j * 16 + c;
        float s = sacc[i][j][r] * SM_SCALE;
        bool valid = (key <= qpos) && (qpos - key <= WIN);
        sv[j] = valid ? s : -3e38f;
        mx = fmaxf(mx, sv[j]);
      }
      #pragma unroll
      for (int msk = 1; msk < 16; msk <<= 1) mx = fmaxf(mx, __shfl_xor(mx, msk, 64));
      mx = fmaxf(mx, sk);
      float sum = 0.f; float pv[9];
      #pragma unroll
      for (int j = 0; j < 9; ++j) { float p = __expf(sv[j] - mx); pv[j] = p; sum += p; }
      #pragma unroll
      for (int msk = 1; msk < 16; msk <<= 1) sum += __shfl_xor(sum, msk, 64);
      sum += __expf(sk - mx);
      float inv = 1.0f / sum;
      int mrow = qm * 16 + quad * 4 + r;
      #pragma unroll
      for (int j = 0; j < 9; ++j)
        Ps[mrow * 160 + j * 16 + c] = f2h(pv[j] * inv);
    }
  }

  __syncthreads();   // Vt + Ps pads + P visible to all waves

  // ---- O = P V via MFMA (5 k-steps of 32 keys, tail zero-padded) ----
  f32x4 oacc[2][4] = {};
  #pragma unroll
  for (int ks = 0; ks < 5; ++ks) {
    half8 ap[2], bv[4];
    #pragma unroll
    for (int i = 0; i < 2; ++i)
      ap[i] = *(const half8*)&Ps[((wave * 2 + i) * 16 + c) * 160 + ks * 32 + quad * 8];
    #pragma unroll
    for (int j = 0; j < 4; ++j)
      bv[j] = *(const half8*)&Vt[(j * 16 + c) * 160 + ks * 32 + quad * 8];
    #pragma unroll
    for (int i = 0; i < 2; ++i)
      #pragma unroll
      for (int j = 0; j < 4; ++j)
        oacc[i][j] = __builtin_amdgcn_mfma_f32_16x16x32_f16(ap[i], bv[j], oacc[i][j], 0, 0, 0);
  }

  #pragma unroll
  for (int i = 0; i < 2; ++i) {
    int qm = wave * 2 + i;
    #pragma unroll
    for (int j = 0; j < 4; ++j)
      #pragma unroll
      for (int r = 0; r < 4; ++r) {
        int token = Q0 + quad * 4 + r;
        attn_out[(size_t)token * 4096 + (kvh * 8 + qm) * 64 + j * 16 + c] = f2h(oacc[i][j][r]);
      }
  }
}

// ---------------- launch ----------------
extern "C" void kernel_launch(void* const* d_in, const int* in_sizes, int n_in,
                              void* d_out, int out_size, void* d_ws, size_t ws_size,
                              hipStream_t stream) {
  (void)in_sizes; (void)n_in; (void)out_size; (void)ws_size;
  const float* x      = (const float*)d_in[0];
  const float* scale  = (const float*)d_in[1];
  const float* sink   = (const float*)d_in[2];
  const float* w_qkv  = (const float*)d_in[3];
  const float* b_qkv  = (const float*)d_in[4];
  const float* w_o    = (const float*)d_in[5];
  const float* b_o    = (const float*)d_in[6];
  float* out = (float*)d_out;

  char* ws = (char*)d_ws;
  size_t off = 0;
  auto alloc = [&](size_t bytes) { void* p = ws + off; off += (bytes + 255) & ~(size_t)255; return p; };
  float2*   tab   = (float2*)alloc((size_t)NTOK * 32 * sizeof(float2));   // 0.5 MB
  _Float16* a_h   = (_Float16*)alloc((size_t)NTOK * HIDDEN * 2);   // 11.8 MB
  _Float16* wtq   = (_Float16*)alloc((size_t)QKV_N * HIDDEN * 2);  // 29.5 MB  [N][K]
  _Float16* wto   = (_Float16*)alloc((size_t)2944 * OPROJ_K * 2);  // 24.1 MB  [Npad][K]
  _Float16* qkv_h = (_Float16*)alloc((size_t)NTOK * QKV_N * 2);    // 21.0 MB (rope applied)
  _Float16* at_h  = (_Float16*)alloc((size_t)NTOK * 4096 * 2);     // 16.8 MB

  int prep_blocks = NB_CQ + NB_CO + NTOK + NB_ROPE;   // 28480
  prep_kernel<<<prep_blocks, 256, 0, stream>>>(x, scale, w_qkv, w_o, a_h, wtq, wto, tab);
  gemm_kernel<128, true><<<dim3(QKV_N / 128, NTOK / 128), 256, 0, stream>>>(
      a_h, wtq, b_qkv, nullptr, tab, qkv_h, NTOK, QKV_N, HIDDEN);
  attn_kernel<<<dim3(NTOK / TQ, 8), 256, 0, stream>>>(qkv_h, sink, at_h);
  gemm_kernel<64, false><<<dim3(23, NTOK / 64), 256, 0, stream>>>(
      at_h, wto, b_o, x, nullptr, out, NTOK, HIDDEN, OPROJ_K);
}

// Round 5
// 336.387 us; speedup vs baseline: 1.2409x; 1.0213x over previous
//
#include <hip/hip_runtime.h>
#include <cstdint>
#include <cstddef>

#define HIDDEN   2880
#define QKV_N    5120      // (64 + 2*8)*64
#define OPROJ_K  4096      // 64*64
#define NTOK     2048
#define WIN      128
#define SM_SCALE 0.125f

typedef _Float16 half8  __attribute__((ext_vector_type(8)));
typedef _Float16 half4v __attribute__((ext_vector_type(4)));
typedef float    f32x4  __attribute__((ext_vector_type(4)));

__device__ __forceinline__ void gload16(const void* g, void* l) {
  // async global->LDS, 16B per lane; LDS dest = wave-uniform base + lane*16
  __builtin_amdgcn_global_load_lds((__attribute__((address_space(1))) void*)g,
                                   (__attribute__((address_space(3))) void*)l,
                                   16, 0, 0);
}

__device__ __forceinline__ _Float16 f2h(float f) { return (_Float16)f; }

// ================= merged prep kernel =================
// blocks [0, NB_T0)      : cast+transpose w_qkv -> wtq[5120][2880] f16 (64x64 tiles)
// blocks [.., +NB_T1)    : cast+transpose w_o   -> wto[2944][4096] f16 (rows>=2880 zero)
// blocks [.., +NTOK)     : rmsnorm row
// blocks [.., +NB_ROPE)  : YaRN rope table
#define NB_T0  (80 * 45)
#define NB_T1  (46 * 64)
#define NB_ROPE 256

__device__ __forceinline__ void cast_transpose64(const float* __restrict__ W,
                                                 _Float16* __restrict__ Wt,
                                                 int K, int N, int n0, int k0,
                                                 float* tile /*64x65*/) {
  int t = threadIdx.x;
  #pragma unroll
  for (int p = 0; p < 16; ++p) {
    int r = p * 4 + (t >> 6), cc = t & 63;     // r = k-local, cc = n-local
    float vv = 0.f;
    if (n0 + cc < N) vv = W[(size_t)(k0 + r) * N + n0 + cc];
    tile[r * 65 + cc] = vv;
  }
  __syncthreads();
  #pragma unroll
  for (int p = 0; p < 2; ++p) {
    int idx = p * 256 + t;
    int r = idx >> 3, ch = (idx & 7) * 8;      // r = n-local, ch = k-local
    half8 h;
    #pragma unroll
    for (int u = 0; u < 8; ++u) h[u] = (_Float16)tile[(ch + u) * 65 + r];
    *(half8*)&Wt[(size_t)(n0 + r) * K + k0 + ch] = h;
  }
}

__global__ __launch_bounds__(256) void prep_kernel(const float* __restrict__ x,
                                                   const float* __restrict__ scale,
                                                   const float* __restrict__ w_qkv,
                                                   const float* __restrict__ w_o,
                                                   _Float16* __restrict__ a_h,
                                                   _Float16* __restrict__ wtq,
                                                   _Float16* __restrict__ wto,
                                                   float2* __restrict__ tab) {
  __shared__ float smem[64 * 65];
  int b = blockIdx.x, t = threadIdx.x;
  if (b < NB_T0) {
    cast_transpose64(w_qkv, wtq, HIDDEN, QKV_N, (b % 80) * 64, (b / 80) * 64, smem);
    return;
  }
  b -= NB_T0;
  if (b < NB_T1) {
    cast_transpose64(w_o, wto, OPROJ_K, HIDDEN, (b % 46) * 64, (b / 46) * 64, smem);
    return;
  }
  b -= NB_T1;
  if (b < NTOK) {
    // ---- RMSNorm row b: fp32 -> f16 normalized*scale ----
    int row = b;
    const float4* xr = (const float4*)(x + (size_t)row * HIDDEN);
    const float4* sc = (const float4*)scale;
    float4 v0 = xr[t];
    float4 v1 = xr[t + 256];
    float4 v2 = (t < 208) ? xr[t + 512] : make_float4(0.f, 0.f, 0.f, 0.f);
    float ss = v0.x*v0.x + v0.y*v0.y + v0.z*v0.z + v0.w*v0.w
             + v1.x*v1.x + v1.y*v1.y + v1.z*v1.z + v1.w*v1.w
             + v2.x*v2.x + v2.y*v2.y + v2.z*v2.z + v2.w*v2.w;
    #pragma unroll
    for (int m = 1; m < 64; m <<= 1) ss += __shfl_xor(ss, m, 64);
    if ((t & 63) == 0) smem[t >> 6] = ss;
    __syncthreads();
    float inv = 1.0f / sqrtf((smem[0] + smem[1] + smem[2] + smem[3]) * (1.0f / HIDDEN) + 1e-5f);
    _Float16* orow = a_h + (size_t)row * HIDDEN;
    auto store4 = [&](int c4, const float4& v, const float4& s) {
      half4v h;
      h[0] = f2h(v.x * inv * s.x); h[1] = f2h(v.y * inv * s.y);
      h[2] = f2h(v.z * inv * s.z); h[3] = f2h(v.w * inv * s.w);
      *(half4v*)(orow + (size_t)c4 * 4) = h;
    };
    store4(t, v0, sc[t]);
    store4(t + 256, v1, sc[t + 256]);
    if (t < 208) store4(t + 512, v2, sc[t + 512]);
    return;
  }
  b -= NTOK;
  {
    // ---- YaRN rope table: tab[tok][d] = (cos,sin)*conc, d<32 ----
    int idx = b * 256 + t;               // 2048*32
    int tok = idx >> 5, d = idx & 31;
    const double PI = 3.14159265358979323846;
    double i = (double)d;
    double lf = log(150000.0);
    double freq = exp(lf * (i / 32.0));
    double interp = 1.0 / (32.0 * freq);
    double extrap = 1.0 / freq;
    double low  = 32.0 * log(4096.0 / (32.0 * 2.0 * PI)) / lf;
    double high = 32.0 * log(4096.0 / (2.0 * PI)) / lf;
    double ramp = (i - low) / (high - low);
    double mm = 1.0 - fmin(fmax(ramp, 0.0), 1.0);
    double invf = interp * (1.0 - mm) + extrap * mm;
    double ang = (double)tok * invf;
    double conc = 0.1 * log(32.0) + 1.0;
    tab[idx] = make_float2((float)(cos(ang) * conc), (float)(sin(ang) * conc));
  }
}

// ---------------- f16 MFMA GEMM: C[M][N] = A[M][K] * Bt[N][K]^T + bias ----------------
// BM x 128 tile, BK=64, 256 thr = 4 waves (2x2), wave tile (BM/2) x 64.
// LDS chunk swizzle: physical 16B chunk = logical ^ (row&7)  -> conflict-free ds_read_b128.
// QKV_MODE: f16 out with fused YaRN RoPE on cols < 4608 (q,k heads); else fp32 out + resid.
template <int BM, bool QKV_MODE, int MINW>
__global__ __launch_bounds__(256, MINW) void gemm_kernel(const _Float16* __restrict__ A,
                                                         const _Float16* __restrict__ Bt,
                                                         const float* __restrict__ bias,
                                                         const float* __restrict__ resid,
                                                         const float2* __restrict__ tab,
                                                         void* __restrict__ Cout,
                                                         int M, int N, int K) {
  constexpr int MI = BM / 32;            // 16-row tiles per wave
  constexpr int NA = BM / 32;            // A gload16 per thread (BM*8/256)
  __shared__ _Float16 Alds[BM * 64];
  __shared__ _Float16 Blds[128 * 64];
  int tid = threadIdx.x;
  int wave = tid >> 6, lane = tid & 63;
  int wm = wave >> 1, wn = wave & 1;
  int c = lane & 15, quad = lane >> 4;
  int m0 = blockIdx.y * BM, n0 = blockIdx.x * 128;

  const _Float16* gAp[NA]; _Float16* lAp[NA];
  #pragma unroll
  for (int i = 0; i < NA; ++i) {
    int p = wave * 64 + i * 256 + lane;
    int r = p >> 3;
    int kl = (p & 7) ^ (r & 7);
    gAp[i] = A + (size_t)(m0 + r) * K + kl * 8;
    lAp[i] = Alds + (size_t)(wave * 64 + i * 256) * 8;
  }
  const _Float16* gBp[4]; _Float16* lBp[4];
  #pragma unroll
  for (int i = 0; i < 4; ++i) {
    int p = wave * 64 + i * 256 + lane;
    int r = p >> 3;
    int kl = (p & 7) ^ (r & 7);
    gBp[i] = Bt + (size_t)(n0 + r) * K + kl * 8;
    lBp[i] = Blds + (size_t)(wave * 64 + i * 256) * 8;
  }

  int px[2];                             // swizzled chunk offsets (in halves)
  px[0] = ((0 * 4 + quad) ^ (c & 7)) * 8;
  px[1] = ((1 * 4 + quad) ^ (c & 7)) * 8;

  f32x4 acc[MI][4] = {};
  int nIter = K >> 6;
  for (int kt = 0; kt < nIter; ++kt) {
    __syncthreads();                 // previous iter's LDS reads done
    #pragma unroll
    for (int i = 0; i < NA; ++i) { gload16(gAp[i], lAp[i]); gAp[i] += 64; }
    #pragma unroll
    for (int i = 0; i < 4; ++i)  { gload16(gBp[i], lBp[i]); gBp[i] += 64; }
    __syncthreads();                 // vmcnt drained -> tiles visible
    half8 a[MI][2], b[4][2];
    #pragma unroll
    for (int i = 0; i < MI; ++i) {
      int row = wm * (BM / 2) + i * 16 + c;
      a[i][0] = *(const half8*)&Alds[row * 64 + px[0]];
      a[i][1] = *(const half8*)&Alds[row * 64 + px[1]];
    }
    #pragma unroll
    for (int j = 0; j < 4; ++j) {
      int row = wn * 64 + j * 16 + c;
      b[j][0] = *(const half8*)&Blds[row * 64 + px[0]];
      b[j][1] = *(const half8*)&Blds[row * 64 + px[1]];
    }
    #pragma unroll
    for (int i = 0; i < MI; ++i)
      #pragma unroll
      for (int j = 0; j < 4; ++j) {
        acc[i][j] = __builtin_amdgcn_mfma_f32_16x16x32_f16(a[i][0], b[j][0], acc[i][j], 0, 0, 0);
        acc[i][j] = __builtin_amdgcn_mfma_f32_16x16x32_f16(a[i][1], b[j][1], acc[i][j], 0, 0, 0);
      }
  }

  // epilogue: C layout col=lane&15, row=quad*4+reg
  if (QKV_MODE) {
    _Float16* outp = (_Float16*)Cout;
    bool ropeTile = (n0 < 4608);       // tiles 0..35 = q,k heads; 36..39 = v passthrough
    #pragma unroll
    for (int i = 0; i < MI; ++i) {
      int rowb = m0 + wm * (BM / 2) + i * 16 + quad * 4;
      if (ropeTile) {
        #pragma unroll
        for (int jp = 0; jp < 2; ++jp) {
          int col = n0 + wn * 64 + jp * 16 + c;   // d = jp*16+c (<32), partner at +32
          float b1 = bias[col], b2 = bias[col + 32];
          #pragma unroll
          for (int r = 0; r < 4; ++r) {
            float2 cs = tab[(size_t)(rowb + r) * 32 + jp * 16 + c];
            float x1 = acc[i][jp][r] + b1;
            float x2 = acc[i][jp + 2][r] + b2;
            outp[(size_t)(rowb + r) * QKV_N + col]      = f2h(x1 * cs.x - x2 * cs.y);
            outp[(size_t)(rowb + r) * QKV_N + col + 32] = f2h(x2 * cs.x + x1 * cs.y);
          }
        }
      } else {
        #pragma unroll
        for (int j = 0; j < 4; ++j) {
          int col = n0 + wn * 64 + j * 16 + c;
          float bv = bias[col];
          #pragma unroll
          for (int r = 0; r < 4; ++r)
            outp[(size_t)(rowb + r) * QKV_N + col] = f2h(acc[i][j][r] + bv);
        }
      }
    }
  } else {
    float* outp = (float*)Cout;
    #pragma unroll
    for (int i = 0; i < MI; ++i) {
      int rowb = m0 + wm * (BM / 2) + i * 16 + quad * 4;
      #pragma unroll
      for (int j = 0; j < 4; ++j) {
        int col = n0 + wn * 64 + j * 16 + c;
        if (col < N) {
          float bv = bias[col];
          #pragma unroll
          for (int r = 0; r < 4; ++r)
            outp[(size_t)(rowb + r) * N + col] =
                acc[i][j][r] + bv + resid[(size_t)(rowb + r) * N + col];
        }
      }
    }
  }
}

// ---------------- sliding-window GQA attention with sink ----------------
// block = (q-tile of 16 tokens) x (kv head). K,Q staged via global_load_lds (swizzled);
// Ps aliases the dead K/Q region after QK^T. LDS total 60 KB.
#define TQ 16
__global__ __launch_bounds__(256) void attn_kernel(const _Float16* __restrict__ qkv,
                                                   const float* __restrict__ sink,
                                                   _Float16* __restrict__ attn_out) {
  __shared__ __align__(16) char smem[61440];
  _Float16* Klds = (_Float16*)smem;             // [160 keys][64 d] swizzled, 20480 B
  _Float16* Qlds = (_Float16*)(smem + 20480);   // [16 tok][8 qm][64 d] swizzled, 16384 B
  _Float16* Ps   = (_Float16*)smem;             // [128 m][160 key] f16, 40960 B (aliases K,Q)
  _Float16* Vt   = (_Float16*)(smem + 40960);   // [64 d][160 key], 20480 B

  int qt = blockIdx.x, kvh = blockIdx.y;
  int Q0 = qt * TQ;
  int kmin = (Q0 >= WIN) ? Q0 - WIN : 0;
  int nkv = Q0 + TQ - kmin;            // valid keys (<=144)
  int tid = threadIdx.x;
  int wave = tid >> 6, lane = tid & 63;
  int c = lane & 15, quad = lane >> 4;

  // ---- stage K rows kmin..kmin+159 (OOB rows land in tab slack, finite) ----
  // LDS chunk ci = row*8+pc; logical chunk = pc ^ (row&7)
  {
    const _Float16* kbase = qkv + 4096 + kvh * 64;
    #pragma unroll
    for (int p = 0; p < 5; ++p) {
      int ci = p * 256 + wave * 64 + lane;
      int row = ci >> 3, pc = ci & 7;
      int lc = pc ^ (row & 7);
      gload16(kbase + (size_t)(kmin + row) * QKV_N + lc * 8,
              (char*)Klds + (size_t)(p * 256 + wave * 64) * 16);
    }
  }
  // ---- stage Q: 16 tokens x 8 heads x 64 d; ci = tok*64 + Lp; Llog = (Lp&56)|((Lp^tok)&7) ----
  {
    const _Float16* qbase = qkv + kvh * 512;
    #pragma unroll
    for (int p = 0; p < 4; ++p) {
      int ci = p * 256 + wave * 64 + lane;
      int tok = ci >> 6, Lp = ci & 63;
      int Llog = (Lp & 56) | ((Lp ^ tok) & 7);
      gload16(qbase + (size_t)(Q0 + tok) * QKV_N + Llog * 8,
              (char*)Qlds + (size_t)(p * 256 + wave * 64) * 16);
    }
  }
  // ---- stage V^T into LDS (zero padding cols); v at qkv col 4608 + kvh*64 ----
  #pragma unroll
  for (int p = 0; p < 5; ++p) {
    int cc = p * 256 + tid;            // 8 d-chunks x 160 cols = 1280
    int col = cc % 160;
    int d0 = (cc / 160) * 8;
    union { uint4 u4; _Float16 hv[8]; } buf;
    if (col < nkv) buf.u4 = *(const uint4*)(qkv + (size_t)(kmin + col) * QKV_N + 4608 + kvh * 64 + d0);
    else           buf.u4 = make_uint4(0, 0, 0, 0);
    #pragma unroll
    for (int uu = 0; uu < 8; ++uu) Vt[(d0 + uu) * 160 + col] = buf.hv[uu];
  }

  __syncthreads();   // staging visible (drains vmcnt for global_load_lds)

  // ---- Q fragments from LDS (A-layout: m=c -> token Q0+c, k=quad*8 + ks*32) ----
  half8 aq[2][2];
  #pragma unroll
  for (int i = 0; i < 2; ++i) {
    int qm = wave * 2 + i;
    #pragma unroll
    for (int ks = 0; ks < 2; ++ks) {
      int kc = ks * 4 + quad;
      int Lp = qm * 8 + (kc ^ (c & 7));
      aq[i][ks] = *(const half8*)&Qlds[c * 512 + Lp * 8];
    }
  }

  // ---- S = Q K^T via MFMA, B-frags from Klds ----
  f32x4 sacc[2][9] = {};
  #pragma unroll
  for (int j = 0; j < 9; ++j) {
    #pragma unroll
    for (int ks = 0; ks < 2; ++ks) {
      int kc = ks * 4 + quad;
      int pc = kc ^ (c & 7);
      half8 bk = *(const half8*)&Klds[(j * 16 + c) * 64 + pc * 8];
      #pragma unroll
      for (int i = 0; i < 2; ++i)
        sacc[i][j] = __builtin_amdgcn_mfma_f32_16x16x32_f16(aq[i][ks], bk, sacc[i][j], 0, 0, 0);
    }
  }

  __syncthreads();   // all waves done reading Klds/Qlds; Ps may now overwrite

  // ---- zero Ps pad columns 144..159 ----
  #pragma unroll
  for (int p = 0; p < 8; ++p) {
    int idx = p * 256 + tid;           // 128 rows x 16 cols
    Ps[(idx >> 4) * 160 + 144 + (idx & 15)] = (_Float16)0.f;
  }

  // ---- in-register softmax (C layout: col=c=key, row=quad*4+r=q) + sink ----
  #pragma unroll
  for (int i = 0; i < 2; ++i) {
    int qm = wave * 2 + i;
    float sk = sink[kvh * 8 + qm];
    #pragma unroll
    for (int r = 0; r < 4; ++r) {
      int qpos = Q0 + quad * 4 + r;
      float sv[9]; float mx = -3e38f;
      #pragma unroll
      for (int j = 0; j < 9; ++j) {
        int key = kmin + j * 16 + c;
        float s = sacc[i][j][r] * SM_SCALE;
        bool valid = (key <= qpos) && (qpos - key <= WIN);
        sv[j] = valid ? s : -3e38f;
        mx = fmaxf(mx, sv[j]);
      }
      #pragma unroll
      for (int msk = 1; msk < 16; msk <<= 1) mx = fmaxf(mx, __shfl_xor(mx, msk, 64));
      mx = fmaxf(mx, sk);
      float sum = 0.f; float pv[9];
      #pragma unroll
      for (int j = 0; j < 9; ++j) { float p = __expf(sv[j] - mx); pv[j] = p; sum += p; }
      #pragma unroll
      for (int msk = 1; msk < 16; msk <<= 1) sum += __shfl_xor(sum, msk, 64);
      sum += __expf(sk - mx);
      float inv = 1.0f / sum;
      int mrow = qm * 16 + quad * 4 + r;
      #pragma unroll
      for (int j = 0; j < 9; ++j)
        Ps[mrow * 160 + j * 16 + c] = f2h(pv[j] * inv);
    }
  }

  __syncthreads();   // Ps + Vt visible to all waves

  // ---- O = P V via MFMA (5 k-steps of 32 keys, tail zero-padded) ----
  f32x4 oacc[2][4] = {};
  #pragma unroll
  for (int ks = 0; ks < 5; ++ks) {
    half8 ap[2], bv[4];
    #pragma unroll
    for (int i = 0; i < 2; ++i)
      ap[i] = *(const half8*)&Ps[((wave * 2 + i) * 16 + c) * 160 + ks * 32 + quad * 8];
    #pragma unroll
    for (int j = 0; j < 4; ++j)
      bv[j] = *(const half8*)&Vt[(j * 16 + c) * 160 + ks * 32 + quad * 8];
    #pragma unroll
    for (int i = 0; i < 2; ++i)
      #pragma unroll
      for (int j = 0; j < 4; ++j)
        oacc[i][j] = __builtin_amdgcn_mfma_f32_16x16x32_f16(ap[i], bv[j], oacc[i][j], 0, 0, 0);
  }

  #pragma unroll
  for (int i = 0; i < 2; ++i) {
    int qm = wave * 2 + i;
    #pragma unroll
    for (int j = 0; j < 4; ++j)
      #pragma unroll
      for (int r = 0; r < 4; ++r) {
        int token = Q0 + quad * 4 + r;
        attn_out[(size_t)token * 4096 + (kvh * 8 + qm) * 64 + j * 16 + c] = f2h(oacc[i][j][r]);
      }
  }
}

// ---------------- launch ----------------
extern "C" void kernel_launch(void* const* d_in, const int* in_sizes, int n_in,
                              void* d_out, int out_size, void* d_ws, size_t ws_size,
                              hipStream_t stream) {
  (void)in_sizes; (void)n_in; (void)out_size; (void)ws_size;
  const float* x      = (const float*)d_in[0];
  const float* scale  = (const float*)d_in[1];
  const float* sink   = (const float*)d_in[2];
  const float* w_qkv  = (const float*)d_in[3];
  const float* b_qkv  = (const float*)d_in[4];
  const float* w_o    = (const float*)d_in[5];
  const float* b_o    = (const float*)d_in[6];
  float* out = (float*)d_out;

  char* ws = (char*)d_ws;
  size_t off = 0;
  auto alloc = [&](size_t bytes) { void* p = ws + off; off += (bytes + 255) & ~(size_t)255; return p; };
  _Float16* wtq   = (_Float16*)alloc((size_t)QKV_N * HIDDEN * 2);  // 29.5 MB, dead after QKV gemm
  _Float16* wto   = (_Float16*)alloc((size_t)2944 * OPROJ_K * 2);  // 24.1 MB
  _Float16* a_h   = (_Float16*)alloc((size_t)NTOK * HIDDEN * 2);   // 11.8 MB
  _Float16* qkv_h = (_Float16*)alloc((size_t)NTOK * QKV_N * 2);    // 21.0 MB
  float2*   tab   = (float2*)alloc((size_t)NTOK * 32 * sizeof(float2)); // 0.5 MB (also K-stage OOB slack)
  _Float16* at_h  = (_Float16*)wtq;                                // 16.8 MB, aliases dead wtq

  int prep_blocks = NB_T0 + NB_T1 + NTOK + NB_ROPE;   // 8848
  prep_kernel<<<prep_blocks, 256, 0, stream>>>(x, scale, w_qkv, w_o, a_h, wtq, wto, tab);
  gemm_kernel<128, true, 3><<<dim3(QKV_N / 128, NTOK / 128), 256, 0, stream>>>(
      a_h, wtq, b_qkv, nullptr, tab, qkv_h, NTOK, QKV_N, HIDDEN);
  attn_kernel<<<dim3(NTOK / TQ, 8), 256, 0, stream>>>(qkv_h, sink, at_h);
  gemm_kernel<64, false, 4><<<dim3(23, NTOK / 64), 256, 0, stream>>>(
      at_h, wto, b_o, x, nullptr, out, NTOK, HIDDEN, OPROJ_K);
}